// Round 1
// baseline (141.617 us; speedup 1.0000x reference)
//
#include <hip/hip_runtime.h>
#include <hip/hip_bf16.h>
#include <math.h>

#define BDIM 512
#define DDIM 512
#define TILE 64
#define BK 16

// ---------------- sim = (A . A^T) / 0.07 ----------------
// 64x64 output tile per 256-thread block, 4x4 register blocking,
// LDS staged K-tiles (k-major layout, +4 pad keeps float4 reads 16B-aligned
// and store-phase bank aliasing at 2-way which is free on gfx950).
__global__ __launch_bounds__(256) void gemm_syrk(const float* __restrict__ A,
                                                 float* __restrict__ S) {
    __shared__ __align__(16) float As[BK][TILE + 4];
    __shared__ __align__(16) float Bs[BK][TILE + 4];
    const int tx = threadIdx.x, ty = threadIdx.y;
    const int lin = ty * 16 + tx;
    const int row0 = blockIdx.y * TILE, col0 = blockIdx.x * TILE;
    float acc[4][4] = {};
    for (int k0 = 0; k0 < DDIM; k0 += BK) {
#pragma unroll
        for (int l = 0; l < 4; ++l) {
            int e = lin + l * 256;
            int r = e >> 4, kk = e & 15;
            As[kk][r] = A[(row0 + r) * DDIM + k0 + kk];
            Bs[kk][r] = A[(col0 + r) * DDIM + k0 + kk];
        }
        __syncthreads();
#pragma unroll
        for (int kk = 0; kk < BK; ++kk) {
            float4 a = *(const float4*)&As[kk][ty * 4];
            float4 b = *(const float4*)&Bs[kk][tx * 4];
            float av[4] = {a.x, a.y, a.z, a.w};
            float bv[4] = {b.x, b.y, b.z, b.w};
#pragma unroll
            for (int i = 0; i < 4; ++i)
#pragma unroll
                for (int j = 0; j < 4; ++j)
                    acc[i][j] = fmaf(av[i], bv[j], acc[i][j]);
        }
        __syncthreads();
    }
    const float scale = 1.0f / 0.07f;
#pragma unroll
    for (int i = 0; i < 4; ++i)
#pragma unroll
        for (int j = 0; j < 4; ++j)
            S[(row0 + ty * 4 + i) * BDIM + col0 + tx * 4 + j] = acc[i][j] * scale;
}

// ---------------- pairwise softplus loss ----------------
// One block per row i. Compact positive/negative sim VALUES into LDS
// (order irrelevant for a sum), then npos x nneg softplus evals:
// outer p (wave-uniform LDS broadcast), inner n (stride-1 LDS).
__global__ __launch_bounds__(256) void pair_loss(const float* __restrict__ S,
                                                 const float* __restrict__ mask,
                                                 const int* __restrict__ sel,
                                                 double* __restrict__ acc) {
    const int i = blockIdx.x;
    if (sel[i] == 0) return;  // sel multiplies both masks; row contributes nothing
    __shared__ float sm[BDIM];
    __shared__ float ps[BDIM];
    __shared__ float ns[BDIM];
    __shared__ int cnt[2];
    __shared__ float wsum[4];
    const int tid = threadIdx.x;
    if (tid < 2) cnt[tid] = 0;
    for (int p = tid; p < BDIM; p += 256) sm[p] = S[i * BDIM + p];
    __syncthreads();
    for (int p = tid; p < BDIM; p += 256) {
        if (p == i) continue;  // logits_mask kills the diagonal
        float m = mask[i * BDIM + p];  // exactly 0.0f or 1.0f
        if (m != 0.0f) { int x = atomicAdd(&cnt[0], 1); ps[x] = sm[p]; }
        else           { int x = atomicAdd(&cnt[1], 1); ns[x] = sm[p]; }
    }
    __syncthreads();
    const int npos = cnt[0], nneg = cnt[1];
    float local = 0.0f;
    for (int pp = 0; pp < npos; ++pp) {
        const float sp = ps[pp];
        for (int nn = tid; nn < nneg; nn += 256) {
            // -log_sigmoid(sp - sn) = softplus(sn - sp), stable form
            float z = ns[nn] - sp;
            float t = fmaxf(z, 0.0f) + __logf(1.0f + __expf(-fabsf(z)));
            local += t;
        }
    }
    // wave64 reduce, then cross-wave via LDS, one double atomic per block
#pragma unroll
    for (int off = 32; off > 0; off >>= 1) local += __shfl_down(local, off, 64);
    const int wave = tid >> 6, lane = tid & 63;
    if (lane == 0) wsum[wave] = local;
    __syncthreads();
    if (tid == 0) {
        double tot = (double)wsum[0] + (double)wsum[1] + (double)wsum[2] + (double)wsum[3];
        atomicAdd(&acc[0], tot);
        atomicAdd(&acc[1], (double)npos * (double)nneg);
    }
}

__global__ void finalize(const double* __restrict__ acc, float* __restrict__ out) {
    double ls = acc[0], pn = acc[1];
    double loss = (pn > 0.0) ? ls / fmax(pn, 1.0) : ls;
    out[0] = (float)loss;
}

extern "C" void kernel_launch(void* const* d_in, const int* in_sizes, int n_in,
                              void* d_out, int out_size, void* d_ws, size_t ws_size,
                              hipStream_t stream) {
    const float* feat = (const float*)d_in[0];   // (512,1,512) == anchor (512,512)
    const float* mask = (const float*)d_in[1];   // (512,512) fp32 {0,1}
    const int*   sel  = (const int*)d_in[2];     // (512,) bool -> int32
    float* out = (float*)d_out;

    float* S = (float*)d_ws;                                       // 512*512*4 = 1 MB
    double* acc = (double*)((char*)d_ws + BDIM * BDIM * sizeof(float));  // 16 B

    hipMemsetAsync(acc, 0, 2 * sizeof(double), stream);
    gemm_syrk<<<dim3(BDIM / TILE, BDIM / TILE), dim3(16, 16), 0, stream>>>(feat, S);
    pair_loss<<<BDIM, 256, 0, stream>>>(S, mask, sel, acc);
    finalize<<<1, 1, 0, stream>>>(acc, out);
}

// Round 2
// 98.104 us; speedup vs baseline: 1.4435x; 1.4435x over previous
//
#include <hip/hip_runtime.h>
#include <hip/hip_bf16.h>
#include <math.h>

#define BDIM 512
#define DDIM 512
#define SPLIT 4     // blocks per row in pair_loss
#define GT 32       // gemm output tile
#define GBK 32      // gemm k-tile

// ---------------- sim = (A . A^T) / 0.07 ----------------
// 32x32 tile per 256-thread block -> 256 blocks (1/CU). float4 global staging,
// k-major LDS with +2 pad (8B-aligned ds_read_b64, worst 2-way banks = free),
// 2x2 register blocking, float2 coalesced stores.
__global__ __launch_bounds__(256) void gemm_syrk(const float* __restrict__ A,
                                                 float* __restrict__ S,
                                                 double* __restrict__ acc) {
    if (blockIdx.x == 0 && blockIdx.y == 0 && threadIdx.x == 0 && threadIdx.y == 0) {
        acc[0] = 0.0; acc[1] = 0.0;   // runs before pair_loss via stream order
    }
    __shared__ __align__(16) float As[GBK][GT + 2];
    __shared__ __align__(16) float Bs[GBK][GT + 2];
    const int tx = threadIdx.x, ty = threadIdx.y;       // 16x16
    const int lin = ty * 16 + tx;
    const int lr = lin >> 3;            // 0..31 tile row for staging
    const int lc = (lin & 7) * 4;       // 0,4,...,28 k-offset for staging
    const int row0 = blockIdx.y * GT, col0 = blockIdx.x * GT;
    float a00 = 0.f, a01 = 0.f, a10 = 0.f, a11 = 0.f;
    for (int k0 = 0; k0 < DDIM; k0 += GBK) {
        float4 av = *(const float4*)&A[(row0 + lr) * DDIM + k0 + lc];
        float4 bv = *(const float4*)&A[(col0 + lr) * DDIM + k0 + lc];
        As[lc + 0][lr] = av.x; As[lc + 1][lr] = av.y;
        As[lc + 2][lr] = av.z; As[lc + 3][lr] = av.w;
        Bs[lc + 0][lr] = bv.x; Bs[lc + 1][lr] = bv.y;
        Bs[lc + 2][lr] = bv.z; Bs[lc + 3][lr] = bv.w;
        __syncthreads();
#pragma unroll
        for (int kk = 0; kk < GBK; ++kk) {
            float x0 = As[kk][ty * 2], x1 = As[kk][ty * 2 + 1];
            float y0 = Bs[kk][tx * 2], y1 = Bs[kk][tx * 2 + 1];
            a00 = fmaf(x0, y0, a00); a01 = fmaf(x0, y1, a01);
            a10 = fmaf(x1, y0, a10); a11 = fmaf(x1, y1, a11);
        }
        __syncthreads();
    }
    const float sc = 1.0f / 0.07f;
    float2 r0 = {a00 * sc, a01 * sc};
    float2 r1 = {a10 * sc, a11 * sc};
    *(float2*)&S[(row0 + ty * 2) * BDIM + col0 + tx * 2]     = r0;
    *(float2*)&S[(row0 + ty * 2 + 1) * BDIM + col0 + tx * 2] = r1;
}

__device__ __forceinline__ float softplus_f(float z) {
    // softplus(z) = -log_sigmoid(-z), stable; returns exactly 0 for z = -inf
    return fmaxf(z, 0.0f) + __logf(1.0f + __expf(-fabsf(z)));
}

// ---------------- pairwise softplus loss ----------------
// SPLIT blocks per row (grid 512*SPLIT). Ballot compaction (2 LDS atomics per
// wave per round). Heavy loop: 4 p-values per outer iter (one ds_read_b128),
// 4 independent accumulator chains for ILP.
__global__ __launch_bounds__(256) void pair_loss(const float* __restrict__ S,
                                                 const float* __restrict__ mask,
                                                 const int* __restrict__ sel,
                                                 double* __restrict__ acc) {
    const int i = blockIdx.x >> 2;     // row
    const int q = blockIdx.x & 3;      // p-chunk
    if (sel[i] == 0) return;           // sel multiplies both masks
    __shared__ float sm[BDIM];
    __shared__ __align__(16) float ps[BDIM + 4];
    __shared__ float ns[BDIM];
    __shared__ int cnt[2];
    __shared__ float wsum[4];
    const int tid = threadIdx.x;
    const int lane = tid & 63, wave = tid >> 6;
    if (tid < 2) cnt[tid] = 0;
    for (int p = tid; p < BDIM; p += 256) sm[p] = S[i * BDIM + p];
    __syncthreads();
#pragma unroll
    for (int r = 0; r < 2; ++r) {
        const int p = tid + r * 256;
        const float m = mask[i * BDIM + p];     // exactly 0.0f or 1.0f
        const bool ok  = (p != i);              // logits_mask kills diagonal
        const bool isp = ok && (m != 0.0f);
        const bool isn = ok && (m == 0.0f);
        unsigned long long bp = __ballot(isp);
        unsigned long long bn = __ballot(isn);
        unsigned long long lower = (1ULL << lane) - 1ULL;
        int pbase = 0, nbase = 0;
        if (lane == 0) {
            pbase = atomicAdd(&cnt[0], __popcll(bp));
            nbase = atomicAdd(&cnt[1], __popcll(bn));
        }
        pbase = __shfl(pbase, 0, 64);
        nbase = __shfl(nbase, 0, 64);
        if (isp) ps[pbase + __popcll(bp & lower)] = sm[p];
        if (isn) ns[nbase + __popcll(bn & lower)] = sm[p];
    }
    __syncthreads();
    const int npos = cnt[0], nneg = cnt[1];
    if (tid < 4) ps[npos + tid] = INFINITY;   // pad: softplus(sn - inf) == 0
    __syncthreads();
    // 4-aligned chunk boundaries partitioning [0, npos)
    int p0 = (q == 0) ? 0 : min(npos, ((q * npos) / SPLIT + 3) & ~3);
    int p1 = (q == SPLIT - 1) ? npos : min(npos, (((q + 1) * npos) / SPLIT + 3) & ~3);
    float l0 = 0.f, l1 = 0.f, l2 = 0.f, l3 = 0.f;
    for (int pp = p0; pp < p1; pp += 4) {
        float4 sp = *(const float4*)&ps[pp];
        for (int nn = tid; nn < nneg; nn += 256) {
            float sn = ns[nn];
            l0 += softplus_f(sn - sp.x);
            l1 += softplus_f(sn - sp.y);
            l2 += softplus_f(sn - sp.z);
            l3 += softplus_f(sn - sp.w);
        }
    }
    float local = (l0 + l1) + (l2 + l3);
#pragma unroll
    for (int off = 32; off > 0; off >>= 1) local += __shfl_down(local, off, 64);
    if (lane == 0) wsum[wave] = local;
    __syncthreads();
    if (tid == 0) {
        double tot = (double)wsum[0] + (double)wsum[1] + (double)wsum[2] + (double)wsum[3];
        atomicAdd(&acc[0], tot);
        if (q == 0) atomicAdd(&acc[1], (double)npos * (double)nneg);
    }
}

__global__ void finalize(const double* __restrict__ acc, float* __restrict__ out) {
    double ls = acc[0], pn = acc[1];
    double loss = (pn > 0.0) ? ls / fmax(pn, 1.0) : ls;
    out[0] = (float)loss;
}

extern "C" void kernel_launch(void* const* d_in, const int* in_sizes, int n_in,
                              void* d_out, int out_size, void* d_ws, size_t ws_size,
                              hipStream_t stream) {
    const float* feat = (const float*)d_in[0];   // (512,1,512) == anchor (512,512)
    const float* mask = (const float*)d_in[1];   // (512,512) fp32 {0,1}
    const int*   sel  = (const int*)d_in[2];     // (512,) bool -> int32
    float* out = (float*)d_out;

    float* S = (float*)d_ws;                                            // 1 MB
    double* acc = (double*)((char*)d_ws + BDIM * BDIM * sizeof(float)); // 16 B

    gemm_syrk<<<dim3(BDIM / GT, BDIM / GT), dim3(16, 16), 0, stream>>>(feat, S, acc);
    pair_loss<<<BDIM * SPLIT, 256, 0, stream>>>(S, mask, sel, acc);
    finalize<<<1, 1, 0, stream>>>(acc, out);
}

// Round 3
// 89.151 us; speedup vs baseline: 1.5885x; 1.1004x over previous
//
#include <hip/hip_runtime.h>
#include <hip/hip_bf16.h>
#include <math.h>

#define BDIM 512
#define DDIM 512
#define SPLIT 4     // blocks per row in pair_loss

typedef __attribute__((ext_vector_type(8))) short bfrag;   // 8 bf16 = 4 VGPRs
typedef __attribute__((ext_vector_type(4))) float ffrag;   // 4 fp32 acc

// ---------------- fp32 -> bf16 convert (+ zero global accumulators) --------
__global__ __launch_bounds__(256) void convert_bf16(const float* __restrict__ A,
                                                    __hip_bfloat16* __restrict__ Ab,
                                                    double* __restrict__ acc) {
    const int idx = (blockIdx.x * 256 + threadIdx.x) * 4;
    if (idx == 0) { acc[0] = 0.0; acc[1] = 0.0; }   // pair_loss is stream-ordered after
    float4 v = *(const float4*)&A[idx];
    union { __hip_bfloat16 h[4]; ushort4 u; } cv;
    cv.h[0] = __float2bfloat16(v.x); cv.h[1] = __float2bfloat16(v.y);
    cv.h[2] = __float2bfloat16(v.z); cv.h[3] = __float2bfloat16(v.w);
    *(ushort4*)&Ab[idx] = cv.u;
}

// ---------------- sim = (A . A^T) / 0.07 via bf16 MFMA ----------------
// One wave per 16x16 output tile; fragments loaded DIRECTLY from global
// (L2-resident, 512 KB). For C = A.A^T both A-frag (A[m=lane&15][k=quad*8+j])
// and B-frag (B[k][n]=A[n][k] -> A[n=lane&15][k=quad*8+j]) are one contiguous
// 16B row chunk per lane: no LDS, no transpose. 256 blocks, 4 waves each.
__global__ __launch_bounds__(256) void gemm_mfma(const __hip_bfloat16* __restrict__ Ab,
                                                 float* __restrict__ S) {
    const int tid = threadIdx.x;
    const int w = tid >> 6, lane = tid & 63;
    const int quad = lane >> 4, r = lane & 15;
    const int m0 = blockIdx.y * 64 + w * 16;   // 4 waves stacked in M
    const int n0 = blockIdx.x * 16;            // shared across waves -> L1 reuse of B
    const __hip_bfloat16* arow = Ab + (m0 + r) * DDIM + quad * 8;
    const __hip_bfloat16* brow = Ab + (n0 + r) * DDIM + quad * 8;
    ffrag acc = {0.f, 0.f, 0.f, 0.f};
#pragma unroll
    for (int k = 0; k < DDIM; k += 32) {
        bfrag af = *(const bfrag*)(arow + k);
        bfrag bf = *(const bfrag*)(brow + k);
        acc = __builtin_amdgcn_mfma_f32_16x16x32_bf16(af, bf, acc, 0, 0, 0);
    }
    const float sc = 1.0f / 0.07f;
    // C/D layout: row = quad*4 + reg, col = lane&15 (m89-verified mapping)
#pragma unroll
    for (int rg = 0; rg < 4; ++rg)
        S[(m0 + quad * 4 + rg) * BDIM + n0 + r] = acc[rg] * sc;
}

__device__ __forceinline__ float softplus_f(float z) {
    // softplus(z) = -log_sigmoid(-z), stable; returns exactly 0 for z = -inf
    return fmaxf(z, 0.0f) + __logf(1.0f + __expf(-fabsf(z)));
}

// ---------------- pairwise softplus loss ----------------
// SPLIT blocks per row. Ballot compaction (2 LDS atomics per wave per round).
// Heavy loop: 4 p-values per outer iter (one ds_read_b128), 4 independent
// accumulator chains for ILP.
__global__ __launch_bounds__(256) void pair_loss(const float* __restrict__ S,
                                                 const float* __restrict__ mask,
                                                 const int* __restrict__ sel,
                                                 double* __restrict__ acc) {
    const int i = blockIdx.x >> 2;     // row
    const int q = blockIdx.x & 3;      // p-chunk
    if (sel[i] == 0) return;           // sel multiplies both masks
    __shared__ float sm[BDIM];
    __shared__ __align__(16) float ps[BDIM + 4];
    __shared__ float ns[BDIM];
    __shared__ int cnt[2];
    __shared__ float wsum[4];
    const int tid = threadIdx.x;
    const int lane = tid & 63, wave = tid >> 6;
    if (tid < 2) cnt[tid] = 0;
    for (int p = tid; p < BDIM; p += 256) sm[p] = S[i * BDIM + p];
    __syncthreads();
#pragma unroll
    for (int r = 0; r < 2; ++r) {
        const int p = tid + r * 256;
        const float m = mask[i * BDIM + p];     // exactly 0.0f or 1.0f
        const bool ok  = (p != i);              // logits_mask kills diagonal
        const bool isp = ok && (m != 0.0f);
        const bool isn = ok && (m == 0.0f);
        unsigned long long bp = __ballot(isp);
        unsigned long long bn = __ballot(isn);
        unsigned long long lower = (1ULL << lane) - 1ULL;
        int pbase = 0, nbase = 0;
        if (lane == 0) {
            pbase = atomicAdd(&cnt[0], __popcll(bp));
            nbase = atomicAdd(&cnt[1], __popcll(bn));
        }
        pbase = __shfl(pbase, 0, 64);
        nbase = __shfl(nbase, 0, 64);
        if (isp) ps[pbase + __popcll(bp & lower)] = sm[p];
        if (isn) ns[nbase + __popcll(bn & lower)] = sm[p];
    }
    __syncthreads();
    const int npos = cnt[0], nneg = cnt[1];
    if (tid < 4) ps[npos + tid] = INFINITY;   // pad: softplus(sn - inf) == 0
    __syncthreads();
    // 4-aligned chunk boundaries partitioning [0, npos)
    int p0 = (q == 0) ? 0 : min(npos, ((q * npos) / SPLIT + 3) & ~3);
    int p1 = (q == SPLIT - 1) ? npos : min(npos, (((q + 1) * npos) / SPLIT + 3) & ~3);
    float l0 = 0.f, l1 = 0.f, l2 = 0.f, l3 = 0.f;
    for (int pp = p0; pp < p1; pp += 4) {
        float4 sp = *(const float4*)&ps[pp];
        for (int nn = tid; nn < nneg; nn += 256) {
            float sn = ns[nn];
            l0 += softplus_f(sn - sp.x);
            l1 += softplus_f(sn - sp.y);
            l2 += softplus_f(sn - sp.z);
            l3 += softplus_f(sn - sp.w);
        }
    }
    float local = (l0 + l1) + (l2 + l3);
#pragma unroll
    for (int off = 32; off > 0; off >>= 1) local += __shfl_down(local, off, 64);
    if (lane == 0) wsum[wave] = local;
    __syncthreads();
    if (tid == 0) {
        double tot = (double)wsum[0] + (double)wsum[1] + (double)wsum[2] + (double)wsum[3];
        atomicAdd(&acc[0], tot);
        if (q == 0) atomicAdd(&acc[1], (double)npos * (double)nneg);
    }
}

__global__ void finalize(const double* __restrict__ acc, float* __restrict__ out) {
    double ls = acc[0], pn = acc[1];
    double loss = (pn > 0.0) ? ls / fmax(pn, 1.0) : ls;
    out[0] = (float)loss;
}

extern "C" void kernel_launch(void* const* d_in, const int* in_sizes, int n_in,
                              void* d_out, int out_size, void* d_ws, size_t ws_size,
                              hipStream_t stream) {
    const float* feat = (const float*)d_in[0];   // (512,1,512) == anchor (512,512)
    const float* mask = (const float*)d_in[1];   // (512,512) fp32 {0,1}
    const int*   sel  = (const int*)d_in[2];     // (512,) bool -> int32
    float* out = (float*)d_out;

    char* ws = (char*)d_ws;
    float* S = (float*)ws;                                   // 1 MB, 16B-aligned
    double* acc = (double*)(ws + BDIM * BDIM * sizeof(float));       // 16 B
    __hip_bfloat16* Ab = (__hip_bfloat16*)(ws + BDIM * BDIM * 4 + 1024);  // 512 KB

    convert_bf16<<<BDIM * DDIM / 1024, 256, 0, stream>>>(feat, Ab, acc);
    gemm_mfma<<<dim3(BDIM / 16, BDIM / 64), 256, 0, stream>>>(Ab, S);
    pair_loss<<<BDIM * SPLIT, 256, 0, stream>>>(S, mask, sel, acc);
    finalize<<<1, 1, 0, stream>>>(acc, out);
}